// Round 1
// baseline (155.908 us; speedup 1.0000x reference)
//
#include <hip/hip_runtime.h>

// ws layout: [0]=pos_sum (f32), [1]=neg_sum (f32), [2]=pos_cnt (u32)

__global__ __launch_bounds__(256) void formicro_reduce(
    const float4* __restrict__ pred4,
    const int4*   __restrict__ ty4,
    int n4, int n_tail, const float* __restrict__ pred_tail,
    const int* __restrict__ ty_tail,
    float* __restrict__ ws)
{
    float pos_acc = 0.f, neg_acc = 0.f;
    unsigned pcnt = 0;

    const int stride = gridDim.x * blockDim.x;
    int gid = blockIdx.x * blockDim.x + threadIdx.x;

    for (int i = gid; i < n4; i += stride) {
        float4 p = pred4[i];
        int4   t = ty4[i];

        #pragma unroll
        for (int c = 0; c < 4; ++c) {
            float pv = (c == 0) ? p.x : (c == 1) ? p.y : (c == 2) ? p.z : p.w;
            int   tv = (c == 0) ? t.x : (c == 1) ? t.y : (c == 2) ? t.z : t.w;
            float a  = fabsf(pv);
            float em = __expf(-a);               // exp(-|p|) in (0,1]
            float lc = __logf(1.0f + em);        // log1p(exp(-|p|)), stable
            float sp_neg = fmaxf(-pv, 0.0f) + lc; // softplus(-p)
            float sp_pos = fmaxf( pv, 0.0f) + lc; // softplus(p)
            bool ispos = (tv == 1);
            pos_acc += ispos ? sp_neg : 0.0f;
            neg_acc += ispos ? 0.0f   : sp_pos;
            pcnt    += ispos ? 1u     : 0u;
        }
    }

    // scalar tail (n not divisible by 4) — handled by the first n_tail threads
    if (gid < n_tail) {
        float pv = pred_tail[gid];
        int   tv = ty_tail[gid];
        float a  = fabsf(pv);
        float em = __expf(-a);
        float lc = __logf(1.0f + em);
        bool ispos = (tv == 1);
        pos_acc += ispos ? (fmaxf(-pv, 0.0f) + lc) : 0.0f;
        neg_acc += ispos ? 0.0f : (fmaxf(pv, 0.0f) + lc);
        pcnt    += ispos ? 1u : 0u;
    }

    // wave-64 reduction
    #pragma unroll
    for (int off = 32; off > 0; off >>= 1) {
        pos_acc += __shfl_down(pos_acc, off);
        neg_acc += __shfl_down(neg_acc, off);
        pcnt    += __shfl_down(pcnt, off);
    }

    __shared__ float    spos[4];
    __shared__ float    sneg[4];
    __shared__ unsigned scnt[4];
    int wid  = threadIdx.x >> 6;
    int lane = threadIdx.x & 63;
    if (lane == 0) { spos[wid] = pos_acc; sneg[wid] = neg_acc; scnt[wid] = pcnt; }
    __syncthreads();

    if (threadIdx.x == 0) {
        float    P = 0.f, Ng = 0.f;
        unsigned C = 0;
        #pragma unroll
        for (int i = 0; i < 4; ++i) { P += spos[i]; Ng += sneg[i]; C += scnt[i]; }
        atomicAdd(&ws[0], P);
        atomicAdd(&ws[1], Ng);
        atomicAdd((unsigned*)&ws[2], C);
    }
}

__global__ void formicro_finalize(const float* __restrict__ ws,
                                  float* __restrict__ out, float total)
{
    unsigned pc = ((const unsigned*)ws)[2];
    float npos = (float)pc;
    float nneg = total - npos;
    out[0] = ws[0] / npos + ws[1] / nneg;
}

extern "C" void kernel_launch(void* const* d_in, const int* in_sizes, int n_in,
                              void* d_out, int out_size, void* d_ws, size_t ws_size,
                              hipStream_t stream)
{
    const float* pred = (const float*)d_in[0];
    const int*   ty   = (const int*)d_in[1];
    float*       out  = (float*)d_out;
    float*       ws   = (float*)d_ws;

    int n  = in_sizes[0];        // 8192*8192 = 67108864, fits in int32
    int n4 = n >> 2;
    int n_tail = n - (n4 << 2);

    hipMemsetAsync(d_ws, 0, 3 * sizeof(float), stream);

    const int block = 256;
    const int grid  = 2048;      // ~8 blocks/CU on 256 CUs; grid-stride covers rest
    formicro_reduce<<<grid, block, 0, stream>>>(
        (const float4*)pred, (const int4*)ty,
        n4, n_tail, pred + (n4 << 2), ty + (n4 << 2), ws);

    formicro_finalize<<<1, 1, 0, stream>>>(ws, out, (float)n);
}

// Round 2
// 110.358 us; speedup vs baseline: 1.4128x; 1.4128x over previous
//
#include <hip/hip_runtime.h>

#define GRID  2048
#define BLOCK 256
#define UNROLL 4

// ws layout: [0..GRID)        pos partials (f32)
//            [GRID..2*GRID)   neg partials (f32)
//            [2*GRID..3*GRID) pos counts  (u32)

__device__ __forceinline__ void proc_elem(float pv, int tv,
                                          float& posd, float& allsp, float& possp,
                                          unsigned& cnt)
{
    float a    = fabsf(pv);
    float em   = __expf(-a);            // exp(-|p|) in (0,1]
    float lc   = __logf(1.0f + em);     // log1p(exp(-|p|)), stable
    float sp   = fmaxf(pv, 0.0f) + lc;  // softplus(p)
    float diff = sp - pv;               // softplus(-p)
    float t    = (float)tv;             // tv in {0,1}
    posd  = fmaf(t, diff, posd);        // sum over pos of softplus(-p)
    allsp += sp;                        // sum over all of softplus(p)
    possp = fmaf(t, sp, possp);         // sum over pos of softplus(p)
    cnt   += (unsigned)tv;
}

__global__ __launch_bounds__(BLOCK) void formicro_reduce(
    const float4* __restrict__ pred4,
    const int4*   __restrict__ ty4,
    int n4,
    const float*  __restrict__ pred_s,
    const int*    __restrict__ ty_s,
    int n,
    float* __restrict__ ws)
{
    const int T   = gridDim.x * blockDim.x;
    const int gid = blockIdx.x * blockDim.x + threadIdx.x;

    float posd = 0.f, allsp = 0.f, possp = 0.f;
    unsigned cnt = 0;

    // main unrolled loop: UNROLL float4+int4 pairs in flight per iteration
    const int nfull = n4 / (UNROLL * T);
    int i = gid;
    for (int g = 0; g < nfull; ++g) {
        float4 P[UNROLL];
        int4   L[UNROLL];
        #pragma unroll
        for (int u = 0; u < UNROLL; ++u) { P[u] = pred4[i + u * T]; }
        #pragma unroll
        for (int u = 0; u < UNROLL; ++u) { L[u] = ty4[i + u * T]; }
        #pragma unroll
        for (int u = 0; u < UNROLL; ++u) {
            proc_elem(P[u].x, L[u].x, posd, allsp, possp, cnt);
            proc_elem(P[u].y, L[u].y, posd, allsp, possp, cnt);
            proc_elem(P[u].z, L[u].z, posd, allsp, possp, cnt);
            proc_elem(P[u].w, L[u].w, posd, allsp, possp, cnt);
        }
        i += UNROLL * T;
    }
    // leftover float4s
    for (; i < n4; i += T) {
        float4 p = pred4[i];
        int4   t = ty4[i];
        proc_elem(p.x, t.x, posd, allsp, possp, cnt);
        proc_elem(p.y, t.y, posd, allsp, possp, cnt);
        proc_elem(p.z, t.z, posd, allsp, possp, cnt);
        proc_elem(p.w, t.w, posd, allsp, possp, cnt);
    }
    // scalar tail (n % 4)
    for (int k = (n4 << 2) + gid; k < n; k += T) {
        proc_elem(pred_s[k], ty_s[k], posd, allsp, possp, cnt);
    }

    float negs = allsp - possp;   // sum over neg of softplus(p)

    // wave-64 reduction
    #pragma unroll
    for (int off = 32; off > 0; off >>= 1) {
        posd += __shfl_down(posd, off);
        negs += __shfl_down(negs, off);
        cnt  += __shfl_down(cnt, off);
    }

    __shared__ float    spos[BLOCK / 64];
    __shared__ float    sneg[BLOCK / 64];
    __shared__ unsigned scnt[BLOCK / 64];
    const int wid  = threadIdx.x >> 6;
    const int lane = threadIdx.x & 63;
    if (lane == 0) { spos[wid] = posd; sneg[wid] = negs; scnt[wid] = cnt; }
    __syncthreads();

    if (threadIdx.x == 0) {
        float P = 0.f, Ng = 0.f;
        unsigned C = 0;
        #pragma unroll
        for (int w = 0; w < BLOCK / 64; ++w) { P += spos[w]; Ng += sneg[w]; C += scnt[w]; }
        ws[blockIdx.x]            = P;
        ws[GRID + blockIdx.x]     = Ng;
        ((unsigned*)ws)[2 * GRID + blockIdx.x] = C;
    }
}

__global__ __launch_bounds__(BLOCK) void formicro_finalize(
    const float* __restrict__ ws, float* __restrict__ out, float total)
{
    float posd = 0.f, negs = 0.f;
    unsigned cnt = 0;
    for (int i = threadIdx.x; i < GRID; i += BLOCK) {
        posd += ws[i];
        negs += ws[GRID + i];
        cnt  += ((const unsigned*)ws)[2 * GRID + i];
    }
    #pragma unroll
    for (int off = 32; off > 0; off >>= 1) {
        posd += __shfl_down(posd, off);
        negs += __shfl_down(negs, off);
        cnt  += __shfl_down(cnt, off);
    }
    __shared__ float    spos[BLOCK / 64];
    __shared__ float    sneg[BLOCK / 64];
    __shared__ unsigned scnt[BLOCK / 64];
    const int wid  = threadIdx.x >> 6;
    const int lane = threadIdx.x & 63;
    if (lane == 0) { spos[wid] = posd; sneg[wid] = negs; scnt[wid] = cnt; }
    __syncthreads();
    if (threadIdx.x == 0) {
        float P = 0.f, Ng = 0.f;
        unsigned C = 0;
        #pragma unroll
        for (int w = 0; w < BLOCK / 64; ++w) { P += spos[w]; Ng += sneg[w]; C += scnt[w]; }
        float npos = (float)C;
        float nneg = total - npos;
        out[0] = P / npos + Ng / nneg;
    }
}

extern "C" void kernel_launch(void* const* d_in, const int* in_sizes, int n_in,
                              void* d_out, int out_size, void* d_ws, size_t ws_size,
                              hipStream_t stream)
{
    const float* pred = (const float*)d_in[0];
    const int*   ty   = (const int*)d_in[1];
    float*       out  = (float*)d_out;
    float*       ws   = (float*)d_ws;

    int n  = in_sizes[0];   // 8192*8192 = 67108864
    int n4 = n >> 2;

    formicro_reduce<<<GRID, BLOCK, 0, stream>>>(
        (const float4*)pred, (const int4*)ty, n4, pred, ty, n, ws);

    formicro_finalize<<<1, BLOCK, 0, stream>>>(ws, out, (float)n);
}